// Round 2
// baseline (252.321 us; speedup 1.0000x reference)
//
#include <hip/hip_runtime.h>
#include <math.h>

// ===== ROUND 2: MEASUREMENT PROBE =====
// Kernels are UNCHANGED from round 1. Both are idempotent (pure functions of the
// inputs overwriting the same buffers), so we launch each 3x. The dur_us delta
// vs round 1 (137.4 us) equals 2*(T_gemm + T_agg), splitting harness floor from
// kernel time. Revert to single launches next round.

#define NN 50001
#define DD 128
#define NE 800000
#define GEMM_BLOCKS 782              // ceil(ceil(50001/16)/4)
#define EDGE_BLOCKS 3125             // ceil(800000/256)
#define WSTRIDE 132                  // LDS row stride in shorts (128+4 pad)

typedef __attribute__((ext_vector_type(8))) short short8;
typedef __attribute__((ext_vector_type(4))) float floatx4;

__device__ __forceinline__ unsigned short f2bf(float f) {
    unsigned u = __builtin_bit_cast(unsigned, f);
    u += 0x7fffu + ((u >> 16) & 1u);          // round-to-nearest-even
    return (unsigned short)(u >> 16);
}
__device__ __forceinline__ float bflo(unsigned u) {   // low 16 bits as bf16 -> f32
    return __builtin_bit_cast(float, u << 16);
}
__device__ __forceinline__ float bfhi(unsigned u) {   // high 16 bits as bf16 -> f32
    return __builtin_bit_cast(float, u & 0xffff0000u);
}
__device__ __forceinline__ float score(float att) {   // leaky-relu(0.2) then exp(x-1)
    att = att >= 0.f ? att : 0.2f * att;
    return __expf(att - 1.f);
}

// K1: blocks < GEMM_BLOCKS: item = emb @ W_scale + b_scale (bf16), fused a_src/a_dst.
//     blocks >= GEMM_BLOCKS: row_ptr[n] = first edge with src >= n (overlaps GEMM).
__global__ void __launch_bounds__(256) k_gemm(const float* __restrict__ emb,
        const float* __restrict__ W, const float* __restrict__ b_scale,
        const float* __restrict__ W_att, const int* __restrict__ edge,
        unsigned short* __restrict__ item, float* __restrict__ a_src,
        float* __restrict__ a_dst, int* __restrict__ row_ptr,
        const float* __restrict__ b_att) {
    if (blockIdx.x >= GEMM_BLOCKS) {                    // ---- rowptr part ----
        int e = (blockIdx.x - GEMM_BLOCKS) * 256 + threadIdx.x;
        if (e >= NE) return;
        int s = edge[2 * e];
        if (e == 0) {
            for (int n = 0; n <= s; n++) row_ptr[n] = 0;
        } else {
            int p = edge[2 * (e - 1)];
            for (int n = p + 1; n <= s; n++) row_ptr[n] = e;
        }
        if (e == NE - 1) {
            for (int n = s + 1; n <= NN; n++) row_ptr[n] = NE;
        }
        return;
    }
    // ---- GEMM part: one wave per 16 nodes ----
    __shared__ unsigned short WTl[DD * WSTRIDE];        // 33792 B, [feature][k]
    {
        const float4* Wv = (const float4*)W;            // 4096 float4s, coalesced
        #pragma unroll
        for (int it = 0; it < 16; it++) {
            int f = it * 256 + threadIdx.x;
            int k = f >> 5;                             // contraction index
            int j4 = (f & 31) * 4;                      // feature columns j4..j4+3
            float4 w = Wv[f];
            WTl[(j4 + 0) * WSTRIDE + k] = f2bf(w.x);
            WTl[(j4 + 1) * WSTRIDE + k] = f2bf(w.y);
            WTl[(j4 + 2) * WSTRIDE + k] = f2bf(w.z);
            WTl[(j4 + 3) * WSTRIDE + k] = f2bf(w.w);
        }
    }
    __syncthreads();

    int wave = blockIdx.x * 4 + (threadIdx.x >> 6);
    int lane = threadIdx.x & 63;
    int base = wave * 16;
    if (base >= NN) return;
    int m = lane & 15, q = lane >> 4;
    int node = base + m;
    bool valid = node < NN;

    int row = valid ? node : NN - 1;
    const float* bp = emb + (long)row * DD + q * 8;
    short8 b[4];                                        // B-frag: emb row (node index)
    #pragma unroll
    for (int ks = 0; ks < 4; ks++) {
        float4 f0 = *(const float4*)(bp + ks * 32);
        float4 f1 = *(const float4*)(bp + ks * 32 + 4);
        b[ks][0] = (short)f2bf(f0.x); b[ks][1] = (short)f2bf(f0.y);
        b[ks][2] = (short)f2bf(f0.z); b[ks][3] = (short)f2bf(f0.w);
        b[ks][4] = (short)f2bf(f1.x); b[ks][5] = (short)f2bf(f1.y);
        b[ks][6] = (short)f2bf(f1.z); b[ks][7] = (short)f2bf(f1.w);
    }

    float p_src = 0.f, p_dst = 0.f;

    #pragma unroll
    for (int ft = 0; ft < 8; ft++) {
        floatx4 acc = {0.f, 0.f, 0.f, 0.f};
        const unsigned short* wrow = WTl + (ft * 16 + m) * WSTRIDE;  // A-frag: feature row
        #pragma unroll
        for (int ks = 0; ks < 4; ks++) {
            short8 a = *(const short8*)(wrow + ks * 32 + q * 8);     // ds_read_b128
            acc = __builtin_amdgcn_mfma_f32_16x16x32_bf16(a, b[ks], acc, 0, 0, 0);
        }
        int fo = ft * 16 + q * 4;
        float4 bs = *(const float4*)(b_scale + fo);
        float4 ws = *(const float4*)(W_att + fo);
        float4 wd = *(const float4*)(W_att + DD + fo);
        float v0 = acc[0] + bs.x, v1 = acc[1] + bs.y;
        float v2 = acc[2] + bs.z, v3 = acc[3] + bs.w;
        if (valid) {
            uint2 pk;
            pk.x = (unsigned)f2bf(v0) | ((unsigned)f2bf(v1) << 16);
            pk.y = (unsigned)f2bf(v2) | ((unsigned)f2bf(v3) << 16);
            *(uint2*)(item + (long)node * DD + fo) = pk;
        }
        p_src += v0 * ws.x + v1 * ws.y + v2 * ws.z + v3 * ws.w;
        p_dst += v0 * wd.x + v1 * wd.y + v2 * wd.z + v3 * wd.w;
    }
    // reduce over q (lane bits 4,5); node is fixed within the reduction
    p_src += __shfl_xor(p_src, 16, 64); p_src += __shfl_xor(p_src, 32, 64);
    p_dst += __shfl_xor(p_dst, 16, 64); p_dst += __shfl_xor(p_dst, 32, 64);
    if (q == 0 && valid) { a_src[node] = p_src + b_att[0]; a_dst[node] = p_dst; }
}

// K2 v2: one 16-lane group per node (unchanged from round 1).
#define ACC8(S, U) \
    acc[0] += (S) * bflo((U).x); acc[1] += (S) * bfhi((U).x); \
    acc[2] += (S) * bflo((U).y); acc[3] += (S) * bfhi((U).y); \
    acc[4] += (S) * bflo((U).z); acc[5] += (S) * bfhi((U).z); \
    acc[6] += (S) * bflo((U).w); acc[7] += (S) * bfhi((U).w);

__global__ void __launch_bounds__(256) k_agg(const int* __restrict__ edge,
        const int* __restrict__ row_ptr, const unsigned short* __restrict__ item,
        const float* __restrict__ a_src, const float* __restrict__ a_dst,
        float* __restrict__ out) {
    int n = blockIdx.x * 16 + (threadIdx.x >> 4);
    int t = threadIdx.x & 15;
    if (n >= NN) return;

    int start = row_ptr[n];
    int len = row_ptr[n + 1] - start;
    float* op = out + (long)n * DD + t * 8;

    if (len <= 0) {
        float4 h = make_float4(0.5f, 0.5f, 0.5f, 0.5f);   // sigmoid(0)
        *(float4*)op = h;
        *(float4*)(op + 4) = h;
        return;
    }

    float asrc = a_src[n];                 // b_att already folded in
    const int* dp = edge + 2 * start + 1;  // dst stream, stride-2 ints
    const unsigned short* ip = item + t * 8;

    float acc[8] = {0.f, 0.f, 0.f, 0.f, 0.f, 0.f, 0.f, 0.f};
    float ssum = 0.f;

    for (int j = 0; j < len; j += 16) {
        int jj = j + t;
        int idx = jj < len ? jj : len - 1;
        int d = dp[2 * idx];               // 16 lanes, contiguous 128 B window
        float x = a_dst[d];                // scattered 4 B, L2-resident (200 KB)
        float s = (jj < len) ? score(asrc + x) : 0.f;
        ssum += s;

        int cnt = len - j;
        if (cnt > 16) cnt = 16;
        int kk = 0;
        for (; kk + 4 <= cnt; kk += 4) {
            int d0 = __shfl(d, kk, 16),     d1 = __shfl(d, kk + 1, 16);
            int d2 = __shfl(d, kk + 2, 16), d3 = __shfl(d, kk + 3, 16);
            float s0 = __shfl(s, kk, 16),     s1 = __shfl(s, kk + 1, 16);
            float s2 = __shfl(s, kk + 2, 16), s3 = __shfl(s, kk + 3, 16);
            uint4 u0 = *(const uint4*)(ip + (long)d0 * DD);
            uint4 u1 = *(const uint4*)(ip + (long)d1 * DD);
            uint4 u2 = *(const uint4*)(ip + (long)d2 * DD);
            uint4 u3 = *(const uint4*)(ip + (long)d3 * DD);
            ACC8(s0, u0);
            ACC8(s1, u1);
            ACC8(s2, u2);
            ACC8(s3, u3);
        }
        for (; kk < cnt; kk++) {
            int d0 = __shfl(d, kk, 16);
            float s0 = __shfl(s, kk, 16);
            uint4 u0 = *(const uint4*)(ip + (long)d0 * DD);
            ACC8(s0, u0);
        }
    }

    // ssum reduce across the 16-lane group only (acc needs no reduction)
    ssum += __shfl_xor(ssum, 1, 16);
    ssum += __shfl_xor(ssum, 2, 16);
    ssum += __shfl_xor(ssum, 4, 16);
    ssum += __shfl_xor(ssum, 8, 16);
    float inv = 1.f / ssum;

    float4 o0, o1;
    o0.x = 1.f / (1.f + __expf(-acc[0] * inv));
    o0.y = 1.f / (1.f + __expf(-acc[1] * inv));
    o0.z = 1.f / (1.f + __expf(-acc[2] * inv));
    o0.w = 1.f / (1.f + __expf(-acc[3] * inv));
    o1.x = 1.f / (1.f + __expf(-acc[4] * inv));
    o1.y = 1.f / (1.f + __expf(-acc[5] * inv));
    o1.z = 1.f / (1.f + __expf(-acc[6] * inv));
    o1.w = 1.f / (1.f + __expf(-acc[7] * inv));
    *(float4*)op = o0;
    *(float4*)(op + 4) = o1;
}

extern "C" void kernel_launch(void* const* d_in, const int* in_sizes, int n_in,
                              void* d_out, int out_size, void* d_ws, size_t ws_size,
                              hipStream_t stream) {
    const int*   edge    = (const int*)d_in[0];
    const float* emb     = (const float*)d_in[1];
    const float* W_scale = (const float*)d_in[2];
    const float* b_scale = (const float*)d_in[3];
    const float* W_att   = (const float*)d_in[4];
    const float* b_att   = (const float*)d_in[5];
    float* out = (float*)d_out;

    char* ws = (char*)d_ws;
    int*            row_ptr = (int*)(ws);                                // 200832 B
    float*          a_src   = (float*)(ws + 200832);                     // 200192 B
    float*          a_dst   = (float*)(ws + 401024);                     // 200192 B
    unsigned short* item    = (unsigned short*)(ws + 601216);            // 12800256 B

    int node_blocks = (NN + 15) / 16;        // one 16-lane group per node

    // PROBE: each kernel launched 3x (idempotent). dur_us - 137.4 = 2*(T_gemm + T_agg).
    k_gemm <<<GEMM_BLOCKS + EDGE_BLOCKS, 256, 0, stream>>>(emb, W_scale, b_scale, W_att,
                                                           edge, item, a_src, a_dst,
                                                           row_ptr, b_att);
    k_gemm <<<GEMM_BLOCKS + EDGE_BLOCKS, 256, 0, stream>>>(emb, W_scale, b_scale, W_att,
                                                           edge, item, a_src, a_dst,
                                                           row_ptr, b_att);
    k_gemm <<<GEMM_BLOCKS + EDGE_BLOCKS, 256, 0, stream>>>(emb, W_scale, b_scale, W_att,
                                                           edge, item, a_src, a_dst,
                                                           row_ptr, b_att);
    k_agg  <<<node_blocks,               256, 0, stream>>>(edge, row_ptr, item,
                                                           a_src, a_dst, out);
    k_agg  <<<node_blocks,               256, 0, stream>>>(edge, row_ptr, item,
                                                           a_src, a_dst, out);
    k_agg  <<<node_blocks,               256, 0, stream>>>(edge, row_ptr, item,
                                                           a_src, a_dst, out);
}

// Round 3
// 245.054 us; speedup vs baseline: 1.0297x; 1.0297x over previous
//
#include <hip/hip_runtime.h>
#include <math.h>

// ===== ROUND 3: ATTRIBUTION PROBE =====
// Kernels byte-identical to round 1, but internally replicated within ONE dispatch
// each (k_gemm GEMM-part x3, k_agg x4; all replicas write identical values -> benign).
// Purpose: push each kernel's dispatch above the 44 us harness fills so its rocprof
// counter row (dur, hbm, VALUBusy, occupancy) appears in top-5. Revert next round.

#define NN 50001
#define DD 128
#define NE 800000
#define GEMM_BLOCKS 782              // ceil(ceil(50001/16)/4)
#define EDGE_BLOCKS 3125             // ceil(800000/256)
#define WSTRIDE 132                  // LDS row stride in shorts (128+4 pad)
#define REP_G 3                      // k_gemm internal replication
#define REP_A 4                      // k_agg internal replication

typedef __attribute__((ext_vector_type(8))) short short8;
typedef __attribute__((ext_vector_type(4))) float floatx4;

__device__ __forceinline__ unsigned short f2bf(float f) {
    unsigned u = __builtin_bit_cast(unsigned, f);
    u += 0x7fffu + ((u >> 16) & 1u);          // round-to-nearest-even
    return (unsigned short)(u >> 16);
}
__device__ __forceinline__ float bflo(unsigned u) {   // low 16 bits as bf16 -> f32
    return __builtin_bit_cast(float, u << 16);
}
__device__ __forceinline__ float bfhi(unsigned u) {   // high 16 bits as bf16 -> f32
    return __builtin_bit_cast(float, u & 0xffff0000u);
}
__device__ __forceinline__ float score(float att) {   // leaky-relu(0.2) then exp(x-1)
    att = att >= 0.f ? att : 0.2f * att;
    return __expf(att - 1.f);
}

// K1: blocks < REP_G*GEMM_BLOCKS: item = emb @ W_scale + b_scale (bf16), fused
//     a_src/a_dst (x REP_G replicas, identical values).
//     blocks >= REP_G*GEMM_BLOCKS: row_ptr[n] = first edge with src >= n (x1).
__global__ void __launch_bounds__(256) k_gemm(const float* __restrict__ emb,
        const float* __restrict__ W, const float* __restrict__ b_scale,
        const float* __restrict__ W_att, const int* __restrict__ edge,
        unsigned short* __restrict__ item, float* __restrict__ a_src,
        float* __restrict__ a_dst, int* __restrict__ row_ptr,
        const float* __restrict__ b_att) {
    if (blockIdx.x >= REP_G * GEMM_BLOCKS) {            // ---- rowptr part ----
        int e = (blockIdx.x - REP_G * GEMM_BLOCKS) * 256 + threadIdx.x;
        if (e >= NE) return;
        int s = edge[2 * e];
        if (e == 0) {
            for (int n = 0; n <= s; n++) row_ptr[n] = 0;
        } else {
            int p = edge[2 * (e - 1)];
            for (int n = p + 1; n <= s; n++) row_ptr[n] = e;
        }
        if (e == NE - 1) {
            for (int n = s + 1; n <= NN; n++) row_ptr[n] = NE;
        }
        return;
    }
    // ---- GEMM part: one wave per 16 nodes ----
    int gblk = blockIdx.x % GEMM_BLOCKS;                // replica-folded block id
    __shared__ unsigned short WTl[DD * WSTRIDE];        // 33792 B, [feature][k]
    {
        const float4* Wv = (const float4*)W;            // 4096 float4s, coalesced
        #pragma unroll
        for (int it = 0; it < 16; it++) {
            int f = it * 256 + threadIdx.x;
            int k = f >> 5;                             // contraction index
            int j4 = (f & 31) * 4;                      // feature columns j4..j4+3
            float4 w = Wv[f];
            WTl[(j4 + 0) * WSTRIDE + k] = f2bf(w.x);
            WTl[(j4 + 1) * WSTRIDE + k] = f2bf(w.y);
            WTl[(j4 + 2) * WSTRIDE + k] = f2bf(w.z);
            WTl[(j4 + 3) * WSTRIDE + k] = f2bf(w.w);
        }
    }
    __syncthreads();

    int wave = gblk * 4 + (threadIdx.x >> 6);
    int lane = threadIdx.x & 63;
    int base = wave * 16;
    if (base >= NN) return;
    int m = lane & 15, q = lane >> 4;
    int node = base + m;
    bool valid = node < NN;

    int row = valid ? node : NN - 1;
    const float* bp = emb + (long)row * DD + q * 8;
    short8 b[4];                                        // B-frag: emb row (node index)
    #pragma unroll
    for (int ks = 0; ks < 4; ks++) {
        float4 f0 = *(const float4*)(bp + ks * 32);
        float4 f1 = *(const float4*)(bp + ks * 32 + 4);
        b[ks][0] = (short)f2bf(f0.x); b[ks][1] = (short)f2bf(f0.y);
        b[ks][2] = (short)f2bf(f0.z); b[ks][3] = (short)f2bf(f0.w);
        b[ks][4] = (short)f2bf(f1.x); b[ks][5] = (short)f2bf(f1.y);
        b[ks][6] = (short)f2bf(f1.z); b[ks][7] = (short)f2bf(f1.w);
    }

    float p_src = 0.f, p_dst = 0.f;

    #pragma unroll
    for (int ft = 0; ft < 8; ft++) {
        floatx4 acc = {0.f, 0.f, 0.f, 0.f};
        const unsigned short* wrow = WTl + (ft * 16 + m) * WSTRIDE;  // A-frag: feature row
        #pragma unroll
        for (int ks = 0; ks < 4; ks++) {
            short8 a = *(const short8*)(wrow + ks * 32 + q * 8);     // ds_read_b128
            acc = __builtin_amdgcn_mfma_f32_16x16x32_bf16(a, b[ks], acc, 0, 0, 0);
        }
        int fo = ft * 16 + q * 4;
        float4 bs = *(const float4*)(b_scale + fo);
        float4 ws = *(const float4*)(W_att + fo);
        float4 wd = *(const float4*)(W_att + DD + fo);
        float v0 = acc[0] + bs.x, v1 = acc[1] + bs.y;
        float v2 = acc[2] + bs.z, v3 = acc[3] + bs.w;
        if (valid) {
            uint2 pk;
            pk.x = (unsigned)f2bf(v0) | ((unsigned)f2bf(v1) << 16);
            pk.y = (unsigned)f2bf(v2) | ((unsigned)f2bf(v3) << 16);
            *(uint2*)(item + (long)node * DD + fo) = pk;
        }
        p_src += v0 * ws.x + v1 * ws.y + v2 * ws.z + v3 * ws.w;
        p_dst += v0 * wd.x + v1 * wd.y + v2 * wd.z + v3 * wd.w;
    }
    // reduce over q (lane bits 4,5); node is fixed within the reduction
    p_src += __shfl_xor(p_src, 16, 64); p_src += __shfl_xor(p_src, 32, 64);
    p_dst += __shfl_xor(p_dst, 16, 64); p_dst += __shfl_xor(p_dst, 32, 64);
    if (q == 0 && valid) { a_src[node] = p_src + b_att[0]; a_dst[node] = p_dst; }
}

// K2 v2: one 16-lane group per node (logic unchanged from round 1; x REP_A replicas).
#define ACC8(S, U) \
    acc[0] += (S) * bflo((U).x); acc[1] += (S) * bfhi((U).x); \
    acc[2] += (S) * bflo((U).y); acc[3] += (S) * bfhi((U).y); \
    acc[4] += (S) * bflo((U).z); acc[5] += (S) * bfhi((U).z); \
    acc[6] += (S) * bflo((U).w); acc[7] += (S) * bfhi((U).w);

#define NODE_BLOCKS ((NN + 15) / 16)

__global__ void __launch_bounds__(256) k_agg(const int* __restrict__ edge,
        const int* __restrict__ row_ptr, const unsigned short* __restrict__ item,
        const float* __restrict__ a_src, const float* __restrict__ a_dst,
        float* __restrict__ out) {
    int blk = blockIdx.x % NODE_BLOCKS;                 // replica-folded block id
    int n = blk * 16 + (threadIdx.x >> 4);
    int t = threadIdx.x & 15;
    if (n >= NN) return;

    int start = row_ptr[n];
    int len = row_ptr[n + 1] - start;
    float* op = out + (long)n * DD + t * 8;

    if (len <= 0) {
        float4 h = make_float4(0.5f, 0.5f, 0.5f, 0.5f);   // sigmoid(0)
        *(float4*)op = h;
        *(float4*)(op + 4) = h;
        return;
    }

    float asrc = a_src[n];                 // b_att already folded in
    const int* dp = edge + 2 * start + 1;  // dst stream, stride-2 ints
    const unsigned short* ip = item + t * 8;

    float acc[8] = {0.f, 0.f, 0.f, 0.f, 0.f, 0.f, 0.f, 0.f};
    float ssum = 0.f;

    for (int j = 0; j < len; j += 16) {
        int jj = j + t;
        int idx = jj < len ? jj : len - 1;
        int d = dp[2 * idx];               // 16 lanes, contiguous 128 B window
        float x = a_dst[d];                // scattered 4 B, L2-resident (200 KB)
        float s = (jj < len) ? score(asrc + x) : 0.f;
        ssum += s;

        int cnt = len - j;
        if (cnt > 16) cnt = 16;
        int kk = 0;
        for (; kk + 4 <= cnt; kk += 4) {
            int d0 = __shfl(d, kk, 16),     d1 = __shfl(d, kk + 1, 16);
            int d2 = __shfl(d, kk + 2, 16), d3 = __shfl(d, kk + 3, 16);
            float s0 = __shfl(s, kk, 16),     s1 = __shfl(s, kk + 1, 16);
            float s2 = __shfl(s, kk + 2, 16), s3 = __shfl(s, kk + 3, 16);
            uint4 u0 = *(const uint4*)(ip + (long)d0 * DD);
            uint4 u1 = *(const uint4*)(ip + (long)d1 * DD);
            uint4 u2 = *(const uint4*)(ip + (long)d2 * DD);
            uint4 u3 = *(const uint4*)(ip + (long)d3 * DD);
            ACC8(s0, u0);
            ACC8(s1, u1);
            ACC8(s2, u2);
            ACC8(s3, u3);
        }
        for (; kk < cnt; kk++) {
            int d0 = __shfl(d, kk, 16);
            float s0 = __shfl(s, kk, 16);
            uint4 u0 = *(const uint4*)(ip + (long)d0 * DD);
            ACC8(s0, u0);
        }
    }

    // ssum reduce across the 16-lane group only (acc needs no reduction)
    ssum += __shfl_xor(ssum, 1, 16);
    ssum += __shfl_xor(ssum, 2, 16);
    ssum += __shfl_xor(ssum, 4, 16);
    ssum += __shfl_xor(ssum, 8, 16);
    float inv = 1.f / ssum;

    float4 o0, o1;
    o0.x = 1.f / (1.f + __expf(-acc[0] * inv));
    o0.y = 1.f / (1.f + __expf(-acc[1] * inv));
    o0.z = 1.f / (1.f + __expf(-acc[2] * inv));
    o0.w = 1.f / (1.f + __expf(-acc[3] * inv));
    o1.x = 1.f / (1.f + __expf(-acc[4] * inv));
    o1.y = 1.f / (1.f + __expf(-acc[5] * inv));
    o1.z = 1.f / (1.f + __expf(-acc[6] * inv));
    o1.w = 1.f / (1.f + __expf(-acc[7] * inv));
    *(float4*)op = o0;
    *(float4*)(op + 4) = o1;
}

extern "C" void kernel_launch(void* const* d_in, const int* in_sizes, int n_in,
                              void* d_out, int out_size, void* d_ws, size_t ws_size,
                              hipStream_t stream) {
    const int*   edge    = (const int*)d_in[0];
    const float* emb     = (const float*)d_in[1];
    const float* W_scale = (const float*)d_in[2];
    const float* b_scale = (const float*)d_in[3];
    const float* W_att   = (const float*)d_in[4];
    const float* b_att   = (const float*)d_in[5];
    float* out = (float*)d_out;

    char* ws = (char*)d_ws;
    int*            row_ptr = (int*)(ws);                                // 200832 B
    float*          a_src   = (float*)(ws + 200832);                     // 200192 B
    float*          a_dst   = (float*)(ws + 401024);                     // 200192 B
    unsigned short* item    = (unsigned short*)(ws + 601216);            // 12800256 B

    k_gemm <<<REP_G * GEMM_BLOCKS + EDGE_BLOCKS, 256, 0, stream>>>(emb, W_scale, b_scale,
                                                           W_att, edge, item, a_src,
                                                           a_dst, row_ptr, b_att);
    k_agg  <<<REP_A * NODE_BLOCKS,               256, 0, stream>>>(edge, row_ptr, item,
                                                           a_src, a_dst, out);
}

// Round 5
// 204.328 us; speedup vs baseline: 1.2349x; 1.1993x over previous
//
#include <hip/hip_runtime.h>
#include <math.h>

// ===== ROUND 5: RESUBMIT ROUND-4 PROBE (container infra failure last round) =====
// k_gemm: internally replicated x6 (benign identical writes) so its counter row
//   finally appears in top-5. Edits: packed b32 W-staging writes (half the
//   bank-conflicted LDS writes), b_scale/W_att staged to LDS (epilogue reads
//   LDS broadcast instead of 24 scattered global loads per wave).
// k_agg: single launch, byte-identical to round 1. Ta = dur - floor - Tg_row.

#define NN 50001
#define DD 128
#define NE 800000
#define GEMM_BLOCKS 782              // ceil(ceil(50001/16)/4)
#define EDGE_BLOCKS 3125             // ceil(800000/256)
#define WSTRIDE 132                  // LDS row stride in shorts (128+4 pad)
#define REP_G 6                      // k_gemm internal replication (probe)

typedef __attribute__((ext_vector_type(8))) short short8;
typedef __attribute__((ext_vector_type(4))) float floatx4;

__device__ __forceinline__ unsigned short f2bf(float f) {
    unsigned u = __builtin_bit_cast(unsigned, f);
    u += 0x7fffu + ((u >> 16) & 1u);          // round-to-nearest-even
    return (unsigned short)(u >> 16);
}
__device__ __forceinline__ float bflo(unsigned u) {   // low 16 bits as bf16 -> f32
    return __builtin_bit_cast(float, u << 16);
}
__device__ __forceinline__ float bfhi(unsigned u) {   // high 16 bits as bf16 -> f32
    return __builtin_bit_cast(float, u & 0xffff0000u);
}
__device__ __forceinline__ float score(float att) {   // leaky-relu(0.2) then exp(x-1)
    att = att >= 0.f ? att : 0.2f * att;
    return __expf(att - 1.f);
}

__global__ void __launch_bounds__(256) k_gemm(const float* __restrict__ emb,
        const float* __restrict__ W, const float* __restrict__ b_scale,
        const float* __restrict__ W_att, const int* __restrict__ edge,
        unsigned short* __restrict__ item, float* __restrict__ a_src,
        float* __restrict__ a_dst, int* __restrict__ row_ptr,
        const float* __restrict__ b_att) {
    if (blockIdx.x >= REP_G * GEMM_BLOCKS) {            // ---- rowptr part (x1) ----
        int e = (blockIdx.x - REP_G * GEMM_BLOCKS) * 256 + threadIdx.x;
        if (e >= NE) return;
        int s = edge[2 * e];
        if (e == 0) {
            for (int n = 0; n <= s; n++) row_ptr[n] = 0;
        } else {
            int p = edge[2 * (e - 1)];
            for (int n = p + 1; n <= s; n++) row_ptr[n] = e;
        }
        if (e == NE - 1) {
            for (int n = s + 1; n <= NN; n++) row_ptr[n] = NE;
        }
        return;
    }
    // ---- GEMM part: one wave per 16 nodes ----
    int gblk = blockIdx.x % GEMM_BLOCKS;                // replica-folded block id
    __shared__ unsigned short WTl[DD * WSTRIDE];        // 33792 B, [feature][k]
    __shared__ float SB[DD];                            // b_scale staged
    __shared__ float WA[2 * DD];                        // W_att staged
    {
        // Packed staging: thread handles W[k][j4..j4+3] and W[k+1][j4..j4+3],
        // writes 4x uint (2 bf16 along k) -> 32 ds_write_b32 instead of 64 b16.
        const float4* Wv = (const float4*)W;            // 4096 float4s, coalesced
        #pragma unroll
        for (int it = 0; it < 8; it++) {
            int f = it * 256 + threadIdx.x;             // pair-task id, 2048 total
            int k = (f >> 5) * 2;                       // even contraction index
            int j4 = (f & 31) * 4;                      // feature columns j4..j4+3
            float4 w0 = Wv[k * 32 + (f & 31)];          // W[k][j4..j4+3]
            float4 w1 = Wv[(k + 1) * 32 + (f & 31)];    // W[k+1][j4..j4+3]
            unsigned p0 = (unsigned)f2bf(w0.x) | ((unsigned)f2bf(w1.x) << 16);
            unsigned p1 = (unsigned)f2bf(w0.y) | ((unsigned)f2bf(w1.y) << 16);
            unsigned p2 = (unsigned)f2bf(w0.z) | ((unsigned)f2bf(w1.z) << 16);
            unsigned p3 = (unsigned)f2bf(w0.w) | ((unsigned)f2bf(w1.w) << 16);
            *(unsigned*)(&WTl[(j4 + 0) * WSTRIDE + k]) = p0;
            *(unsigned*)(&WTl[(j4 + 1) * WSTRIDE + k]) = p1;
            *(unsigned*)(&WTl[(j4 + 2) * WSTRIDE + k]) = p2;
            *(unsigned*)(&WTl[(j4 + 3) * WSTRIDE + k]) = p3;
        }
        WA[threadIdx.x] = W_att[threadIdx.x];           // 256 floats = 2*DD
        if (threadIdx.x < DD) SB[threadIdx.x] = b_scale[threadIdx.x];
    }
    __syncthreads();

    int wave = gblk * 4 + (threadIdx.x >> 6);
    int lane = threadIdx.x & 63;
    int base = wave * 16;
    if (base >= NN) return;
    int m = lane & 15, q = lane >> 4;
    int node = base + m;
    bool valid = node < NN;

    int row = valid ? node : NN - 1;
    const float* bp = emb + (long)row * DD + q * 8;
    short8 b[4];                                        // B-frag: emb row (node index)
    #pragma unroll
    for (int ks = 0; ks < 4; ks++) {
        float4 f0 = *(const float4*)(bp + ks * 32);
        float4 f1 = *(const float4*)(bp + ks * 32 + 4);
        b[ks][0] = (short)f2bf(f0.x); b[ks][1] = (short)f2bf(f0.y);
        b[ks][2] = (short)f2bf(f0.z); b[ks][3] = (short)f2bf(f0.w);
        b[ks][4] = (short)f2bf(f1.x); b[ks][5] = (short)f2bf(f1.y);
        b[ks][6] = (short)f2bf(f1.z); b[ks][7] = (short)f2bf(f1.w);
    }

    float p_src = 0.f, p_dst = 0.f;

    #pragma unroll
    for (int ft = 0; ft < 8; ft++) {
        floatx4 acc = {0.f, 0.f, 0.f, 0.f};
        const unsigned short* wrow = WTl + (ft * 16 + m) * WSTRIDE;  // A-frag: feature row
        #pragma unroll
        for (int ks = 0; ks < 4; ks++) {
            short8 a = *(const short8*)(wrow + ks * 32 + q * 8);     // ds_read_b128
            acc = __builtin_amdgcn_mfma_f32_16x16x32_bf16(a, b[ks], acc, 0, 0, 0);
        }
        int fo = ft * 16 + q * 4;
        float4 bs = *(const float4*)(SB + fo);          // LDS broadcast reads
        float4 ws = *(const float4*)(WA + fo);
        float4 wd = *(const float4*)(WA + DD + fo);
        float v0 = acc[0] + bs.x, v1 = acc[1] + bs.y;
        float v2 = acc[2] + bs.z, v3 = acc[3] + bs.w;
        if (valid) {
            uint2 pk;
            pk.x = (unsigned)f2bf(v0) | ((unsigned)f2bf(v1) << 16);
            pk.y = (unsigned)f2bf(v2) | ((unsigned)f2bf(v3) << 16);
            *(uint2*)(item + (long)node * DD + fo) = pk;
        }
        p_src += v0 * ws.x + v1 * ws.y + v2 * ws.z + v3 * ws.w;
        p_dst += v0 * wd.x + v1 * wd.y + v2 * wd.z + v3 * wd.w;
    }
    // reduce over q (lane bits 4,5); node is fixed within the reduction
    p_src += __shfl_xor(p_src, 16, 64); p_src += __shfl_xor(p_src, 32, 64);
    p_dst += __shfl_xor(p_dst, 16, 64); p_dst += __shfl_xor(p_dst, 32, 64);
    if (q == 0 && valid) { a_src[node] = p_src + b_att[0]; a_dst[node] = p_dst; }
}

// K2 v2: one 16-lane group per node (byte-identical to round 1, single launch).
#define ACC8(S, U) \
    acc[0] += (S) * bflo((U).x); acc[1] += (S) * bfhi((U).x); \
    acc[2] += (S) * bflo((U).y); acc[3] += (S) * bfhi((U).y); \
    acc[4] += (S) * bflo((U).z); acc[5] += (S) * bfhi((U).z); \
    acc[6] += (S) * bflo((U).w); acc[7] += (S) * bfhi((U).w);

__global__ void __launch_bounds__(256) k_agg(const int* __restrict__ edge,
        const int* __restrict__ row_ptr, const unsigned short* __restrict__ item,
        const float* __restrict__ a_src, const float* __restrict__ a_dst,
        float* __restrict__ out) {
    int n = blockIdx.x * 16 + (threadIdx.x >> 4);
    int t = threadIdx.x & 15;
    if (n >= NN) return;

    int start = row_ptr[n];
    int len = row_ptr[n + 1] - start;
    float* op = out + (long)n * DD + t * 8;

    if (len <= 0) {
        float4 h = make_float4(0.5f, 0.5f, 0.5f, 0.5f);   // sigmoid(0)
        *(float4*)op = h;
        *(float4*)(op + 4) = h;
        return;
    }

    float asrc = a_src[n];                 // b_att already folded in
    const int* dp = edge + 2 * start + 1;  // dst stream, stride-2 ints
    const unsigned short* ip = item + t * 8;

    float acc[8] = {0.f, 0.f, 0.f, 0.f, 0.f, 0.f, 0.f, 0.f};
    float ssum = 0.f;

    for (int j = 0; j < len; j += 16) {
        int jj = j + t;
        int idx = jj < len ? jj : len - 1;
        int d = dp[2 * idx];               // 16 lanes, contiguous 128 B window
        float x = a_dst[d];                // scattered 4 B, L2-resident (200 KB)
        float s = (jj < len) ? score(asrc + x) : 0.f;
        ssum += s;

        int cnt = len - j;
        if (cnt > 16) cnt = 16;
        int kk = 0;
        for (; kk + 4 <= cnt; kk += 4) {
            int d0 = __shfl(d, kk, 16),     d1 = __shfl(d, kk + 1, 16);
            int d2 = __shfl(d, kk + 2, 16), d3 = __shfl(d, kk + 3, 16);
            float s0 = __shfl(s, kk, 16),     s1 = __shfl(s, kk + 1, 16);
            float s2 = __shfl(s, kk + 2, 16), s3 = __shfl(s, kk + 3, 16);
            uint4 u0 = *(const uint4*)(ip + (long)d0 * DD);
            uint4 u1 = *(const uint4*)(ip + (long)d1 * DD);
            uint4 u2 = *(const uint4*)(ip + (long)d2 * DD);
            uint4 u3 = *(const uint4*)(ip + (long)d3 * DD);
            ACC8(s0, u0);
            ACC8(s1, u1);
            ACC8(s2, u2);
            ACC8(s3, u3);
        }
        for (; kk < cnt; kk++) {
            int d0 = __shfl(d, kk, 16);
            float s0 = __shfl(s, kk, 16);
            uint4 u0 = *(const uint4*)(ip + (long)d0 * DD);
            ACC8(s0, u0);
        }
    }

    // ssum reduce across the 16-lane group only (acc needs no reduction)
    ssum += __shfl_xor(ssum, 1, 16);
    ssum += __shfl_xor(ssum, 2, 16);
    ssum += __shfl_xor(ssum, 4, 16);
    ssum += __shfl_xor(ssum, 8, 16);
    float inv = 1.f / ssum;

    float4 o0, o1;
    o0.x = 1.f / (1.f + __expf(-acc[0] * inv));
    o0.y = 1.f / (1.f + __expf(-acc[1] * inv));
    o0.z = 1.f / (1.f + __expf(-acc[2] * inv));
    o0.w = 1.f / (1.f + __expf(-acc[3] * inv));
    o1.x = 1.f / (1.f + __expf(-acc[4] * inv));
    o1.y = 1.f / (1.f + __expf(-acc[5] * inv));
    o1.z = 1.f / (1.f + __expf(-acc[6] * inv));
    o1.w = 1.f / (1.f + __expf(-acc[7] * inv));
    *(float4*)op = o0;
    *(float4*)(op + 4) = o1;
}

extern "C" void kernel_launch(void* const* d_in, const int* in_sizes, int n_in,
                              void* d_out, int out_size, void* d_ws, size_t ws_size,
                              hipStream_t stream) {
    const int*   edge    = (const int*)d_in[0];
    const float* emb     = (const float*)d_in[1];
    const float* W_scale = (const float*)d_in[2];
    const float* b_scale = (const float*)d_in[3];
    const float* W_att   = (const float*)d_in[4];
    const float* b_att   = (const float*)d_in[5];
    float* out = (float*)d_out;

    char* ws = (char*)d_ws;
    int*            row_ptr = (int*)(ws);                                // 200832 B
    float*          a_src   = (float*)(ws + 200832);                     // 200192 B
    float*          a_dst   = (float*)(ws + 401024);                     // 200192 B
    unsigned short* item    = (unsigned short*)(ws + 601216);            // 12800256 B

    int node_blocks = (NN + 15) / 16;        // one 16-lane group per node

    k_gemm <<<REP_G * GEMM_BLOCKS + EDGE_BLOCKS, 256, 0, stream>>>(emb, W_scale, b_scale,
                                                           W_att, edge, item, a_src,
                                                           a_dst, row_ptr, b_att);
    k_agg  <<<node_blocks,                       256, 0, stream>>>(edge, row_ptr, item,
                                                           a_src, a_dst, out);
}

// Round 6
// 143.142 us; speedup vs baseline: 1.7627x; 1.4275x over previous
//
#include <hip/hip_runtime.h>
#include <math.h>

// ===== ROUND 6: LDS-free k_gemm + one-time W transpose =====
// k_pre: blocks 0..63 transpose W -> WT bf16 (32 KB, workspace) ONCE; blocks
//   64.. build row_ptr (moved out of k_gemm). k_gemm: A-frags read straight
//   from global WT (L1/L2-resident; every wave rereads the same 32 KB); no LDS,
//   no __syncthreads, no bank conflicts, occupancy VGPR-bound (~8 waves/SIMD).
// k_agg: byte-identical to round 1 (clean attribution of the k_gemm change).

#define NN 50001
#define DD 128
#define NE 800000
#define GEMM_BLOCKS 782              // ceil(ceil(50001/16)/4)
#define EDGE_BLOCKS 3125             // ceil(800000/256)
#define TR_BLOCKS 64                 // k_pre transpose blocks (2 cols each)

typedef __attribute__((ext_vector_type(8))) short short8;
typedef __attribute__((ext_vector_type(4))) float floatx4;

__device__ __forceinline__ unsigned short f2bf(float f) {
    unsigned u = __builtin_bit_cast(unsigned, f);
    u += 0x7fffu + ((u >> 16) & 1u);          // round-to-nearest-even
    return (unsigned short)(u >> 16);
}
__device__ __forceinline__ float bflo(unsigned u) {   // low 16 bits as bf16 -> f32
    return __builtin_bit_cast(float, u << 16);
}
__device__ __forceinline__ float bfhi(unsigned u) {   // high 16 bits as bf16 -> f32
    return __builtin_bit_cast(float, u & 0xffff0000u);
}
__device__ __forceinline__ float score(float att) {   // leaky-relu(0.2) then exp(x-1)
    att = att >= 0.f ? att : 0.2f * att;
    return __expf(att - 1.f);
}

// K0: blocks < TR_BLOCKS: WT[j][k] = bf16(W[k][j])  (one-time 32 KB transpose).
//     blocks >= TR_BLOCKS: row_ptr[n] = first edge with src >= n.
__global__ void __launch_bounds__(256) k_pre(const float* __restrict__ W,
        const int* __restrict__ edge, unsigned short* __restrict__ WT,
        int* __restrict__ row_ptr) {
    if (blockIdx.x < TR_BLOCKS) {
        int j = blockIdx.x * 2 + (threadIdx.x >> 7);    // feature column
        int k = threadIdx.x & 127;                      // contraction index
        WT[j * DD + k] = f2bf(W[k * DD + j]);           // strided L2 read, coalesced write
        return;
    }
    int e = (blockIdx.x - TR_BLOCKS) * 256 + threadIdx.x;
    if (e >= NE) return;
    int s = edge[2 * e];
    if (e == 0) {
        for (int n = 0; n <= s; n++) row_ptr[n] = 0;
    } else {
        int p = edge[2 * (e - 1)];
        for (int n = p + 1; n <= s; n++) row_ptr[n] = e;
    }
    if (e == NE - 1) {
        for (int n = s + 1; n <= NN; n++) row_ptr[n] = NE;
    }
}

// K1: item = emb @ W_scale + b_scale (bf16), fused a_src/a_dst. One wave per
// 16 nodes. A-frags from global WT (no LDS at all).
__global__ void __launch_bounds__(256) k_gemm(const float* __restrict__ emb,
        const unsigned short* __restrict__ WT, const float* __restrict__ b_scale,
        const float* __restrict__ W_att, unsigned short* __restrict__ item,
        float* __restrict__ a_src, float* __restrict__ a_dst,
        const float* __restrict__ b_att) {
    int wave = blockIdx.x * 4 + (threadIdx.x >> 6);
    int lane = threadIdx.x & 63;
    int base = wave * 16;
    if (base >= NN) return;
    int m = lane & 15, q = lane >> 4;
    int node = base + m;
    bool valid = node < NN;

    int row = valid ? node : NN - 1;
    const float* bp = emb + (long)row * DD + q * 8;
    short8 b[4];                                        // B-frag: emb row (node index)
    #pragma unroll
    for (int ks = 0; ks < 4; ks++) {
        float4 f0 = *(const float4*)(bp + ks * 32);
        float4 f1 = *(const float4*)(bp + ks * 32 + 4);
        b[ks][0] = (short)f2bf(f0.x); b[ks][1] = (short)f2bf(f0.y);
        b[ks][2] = (short)f2bf(f0.z); b[ks][3] = (short)f2bf(f0.w);
        b[ks][4] = (short)f2bf(f1.x); b[ks][5] = (short)f2bf(f1.y);
        b[ks][6] = (short)f2bf(f1.z); b[ks][7] = (short)f2bf(f1.w);
    }

    float p_src = 0.f, p_dst = 0.f;

    #pragma unroll
    for (int ft = 0; ft < 8; ft++) {
        floatx4 acc = {0.f, 0.f, 0.f, 0.f};
        const unsigned short* wrow = WT + (ft * 16 + m) * DD;  // A-frag: feature row
        #pragma unroll
        for (int ks = 0; ks < 4; ks++) {
            short8 a = *(const short8*)(wrow + ks * 32 + q * 8);   // 16B, L1/L2-resident
            acc = __builtin_amdgcn_mfma_f32_16x16x32_bf16(a, b[ks], acc, 0, 0, 0);
        }
        int fo = ft * 16 + q * 4;
        float4 bs = *(const float4*)(b_scale + fo);
        float4 ws = *(const float4*)(W_att + fo);
        float4 wd = *(const float4*)(W_att + DD + fo);
        float v0 = acc[0] + bs.x, v1 = acc[1] + bs.y;
        float v2 = acc[2] + bs.z, v3 = acc[3] + bs.w;
        if (valid) {
            uint2 pk;
            pk.x = (unsigned)f2bf(v0) | ((unsigned)f2bf(v1) << 16);
            pk.y = (unsigned)f2bf(v2) | ((unsigned)f2bf(v3) << 16);
            *(uint2*)(item + (long)node * DD + fo) = pk;
        }
        p_src += v0 * ws.x + v1 * ws.y + v2 * ws.z + v3 * ws.w;
        p_dst += v0 * wd.x + v1 * wd.y + v2 * wd.z + v3 * wd.w;
    }
    // reduce over q (lane bits 4,5); node is fixed within the reduction
    p_src += __shfl_xor(p_src, 16, 64); p_src += __shfl_xor(p_src, 32, 64);
    p_dst += __shfl_xor(p_dst, 16, 64); p_dst += __shfl_xor(p_dst, 32, 64);
    if (q == 0 && valid) { a_src[node] = p_src + b_att[0]; a_dst[node] = p_dst; }
}

// K2: one 16-lane group per node (byte-identical to round 1).
#define ACC8(S, U) \
    acc[0] += (S) * bflo((U).x); acc[1] += (S) * bfhi((U).x); \
    acc[2] += (S) * bflo((U).y); acc[3] += (S) * bfhi((U).y); \
    acc[4] += (S) * bflo((U).z); acc[5] += (S) * bfhi((U).z); \
    acc[6] += (S) * bflo((U).w); acc[7] += (S) * bfhi((U).w);

__global__ void __launch_bounds__(256) k_agg(const int* __restrict__ edge,
        const int* __restrict__ row_ptr, const unsigned short* __restrict__ item,
        const float* __restrict__ a_src, const float* __restrict__ a_dst,
        float* __restrict__ out) {
    int n = blockIdx.x * 16 + (threadIdx.x >> 4);
    int t = threadIdx.x & 15;
    if (n >= NN) return;

    int start = row_ptr[n];
    int len = row_ptr[n + 1] - start;
    float* op = out + (long)n * DD + t * 8;

    if (len <= 0) {
        float4 h = make_float4(0.5f, 0.5f, 0.5f, 0.5f);   // sigmoid(0)
        *(float4*)op = h;
        *(float4*)(op + 4) = h;
        return;
    }

    float asrc = a_src[n];                 // b_att already folded in
    const int* dp = edge + 2 * start + 1;  // dst stream, stride-2 ints
    const unsigned short* ip = item + t * 8;

    float acc[8] = {0.f, 0.f, 0.f, 0.f, 0.f, 0.f, 0.f, 0.f};
    float ssum = 0.f;

    for (int j = 0; j < len; j += 16) {
        int jj = j + t;
        int idx = jj < len ? jj : len - 1;
        int d = dp[2 * idx];               // 16 lanes, contiguous 128 B window
        float x = a_dst[d];                // scattered 4 B, L2-resident (200 KB)
        float s = (jj < len) ? score(asrc + x) : 0.f;
        ssum += s;

        int cnt = len - j;
        if (cnt > 16) cnt = 16;
        int kk = 0;
        for (; kk + 4 <= cnt; kk += 4) {
            int d0 = __shfl(d, kk, 16),     d1 = __shfl(d, kk + 1, 16);
            int d2 = __shfl(d, kk + 2, 16), d3 = __shfl(d, kk + 3, 16);
            float s0 = __shfl(s, kk, 16),     s1 = __shfl(s, kk + 1, 16);
            float s2 = __shfl(s, kk + 2, 16), s3 = __shfl(s, kk + 3, 16);
            uint4 u0 = *(const uint4*)(ip + (long)d0 * DD);
            uint4 u1 = *(const uint4*)(ip + (long)d1 * DD);
            uint4 u2 = *(const uint4*)(ip + (long)d2 * DD);
            uint4 u3 = *(const uint4*)(ip + (long)d3 * DD);
            ACC8(s0, u0);
            ACC8(s1, u1);
            ACC8(s2, u2);
            ACC8(s3, u3);
        }
        for (; kk < cnt; kk++) {
            int d0 = __shfl(d, kk, 16);
            float s0 = __shfl(s, kk, 16);
            uint4 u0 = *(const uint4*)(ip + (long)d0 * DD);
            ACC8(s0, u0);
        }
    }

    // ssum reduce across the 16-lane group only (acc needs no reduction)
    ssum += __shfl_xor(ssum, 1, 16);
    ssum += __shfl_xor(ssum, 2, 16);
    ssum += __shfl_xor(ssum, 4, 16);
    ssum += __shfl_xor(ssum, 8, 16);
    float inv = 1.f / ssum;

    float4 o0, o1;
    o0.x = 1.f / (1.f + __expf(-acc[0] * inv));
    o0.y = 1.f / (1.f + __expf(-acc[1] * inv));
    o0.z = 1.f / (1.f + __expf(-acc[2] * inv));
    o0.w = 1.f / (1.f + __expf(-acc[3] * inv));
    o1.x = 1.f / (1.f + __expf(-acc[4] * inv));
    o1.y = 1.f / (1.f + __expf(-acc[5] * inv));
    o1.z = 1.f / (1.f + __expf(-acc[6] * inv));
    o1.w = 1.f / (1.f + __expf(-acc[7] * inv));
    *(float4*)op = o0;
    *(float4*)(op + 4) = o1;
}

extern "C" void kernel_launch(void* const* d_in, const int* in_sizes, int n_in,
                              void* d_out, int out_size, void* d_ws, size_t ws_size,
                              hipStream_t stream) {
    const int*   edge    = (const int*)d_in[0];
    const float* emb     = (const float*)d_in[1];
    const float* W_scale = (const float*)d_in[2];
    const float* b_scale = (const float*)d_in[3];
    const float* W_att   = (const float*)d_in[4];
    const float* b_att   = (const float*)d_in[5];
    float* out = (float*)d_out;

    char* ws = (char*)d_ws;
    int*            row_ptr = (int*)(ws);                                // 200832 B
    float*          a_src   = (float*)(ws + 200832);                     // 200192 B
    float*          a_dst   = (float*)(ws + 401024);                     // 200192 B
    unsigned short* item    = (unsigned short*)(ws + 601216);            // 12800256 B
    unsigned short* WT      = (unsigned short*)(ws + 13401472);          // 32768 B

    int node_blocks = (NN + 15) / 16;        // one 16-lane group per node

    k_pre  <<<TR_BLOCKS + EDGE_BLOCKS, 256, 0, stream>>>(W_scale, edge, WT, row_ptr);
    k_gemm <<<GEMM_BLOCKS,             256, 0, stream>>>(emb, WT, b_scale, W_att,
                                                         item, a_src, a_dst, b_att);
    k_agg  <<<node_blocks,             256, 0, stream>>>(edge, row_ptr, item,
                                                         a_src, a_dst, out);
}

// Round 7
// 142.313 us; speedup vs baseline: 1.7730x; 1.0058x over previous
//
#include <hip/hip_runtime.h>
#include <math.h>

// ===== ROUND 7: k_gemm max-MLP (issue all 40 loads before compute) =====
// R6 lesson: both LDS and global-WT k_gemm variants are ~3x over byte floor with
// NOTHING saturated (R5: VALU 20%, hbm 21%, Mfma 4%) -> latency-bound, ~3 waves/SIMD
// (grid-limited) with only 2-4 loads in flight. Fix: preload 8 emb float4 (HBM)
// + all 32 WT short8 frags (L1-hot) into registers up front, then convert+MFMA.
// k_pre / k_agg byte-identical to round 6 for attribution.

#define NN 50001
#define DD 128
#define NE 800000
#define GEMM_BLOCKS 782              // ceil(ceil(50001/16)/4)
#define EDGE_BLOCKS 3125             // ceil(800000/256)
#define TR_BLOCKS 64                 // k_pre transpose blocks (2 cols each)

typedef __attribute__((ext_vector_type(8))) short short8;
typedef __attribute__((ext_vector_type(4))) float floatx4;

__device__ __forceinline__ unsigned short f2bf(float f) {
    unsigned u = __builtin_bit_cast(unsigned, f);
    u += 0x7fffu + ((u >> 16) & 1u);          // round-to-nearest-even
    return (unsigned short)(u >> 16);
}
__device__ __forceinline__ float bflo(unsigned u) {   // low 16 bits as bf16 -> f32
    return __builtin_bit_cast(float, u << 16);
}
__device__ __forceinline__ float bfhi(unsigned u) {   // high 16 bits as bf16 -> f32
    return __builtin_bit_cast(float, u & 0xffff0000u);
}
__device__ __forceinline__ float score(float att) {   // leaky-relu(0.2) then exp(x-1)
    att = att >= 0.f ? att : 0.2f * att;
    return __expf(att - 1.f);
}

// K0: blocks < TR_BLOCKS: WT[j][k] = bf16(W[k][j])  (one-time 32 KB transpose).
//     blocks >= TR_BLOCKS: row_ptr[n] = first edge with src >= n.
__global__ void __launch_bounds__(256) k_pre(const float* __restrict__ W,
        const int* __restrict__ edge, unsigned short* __restrict__ WT,
        int* __restrict__ row_ptr) {
    if (blockIdx.x < TR_BLOCKS) {
        int j = blockIdx.x * 2 + (threadIdx.x >> 7);    // feature column
        int k = threadIdx.x & 127;                      // contraction index
        WT[j * DD + k] = f2bf(W[k * DD + j]);           // strided L2 read, coalesced write
        return;
    }
    int e = (blockIdx.x - TR_BLOCKS) * 256 + threadIdx.x;
    if (e >= NE) return;
    int s = edge[2 * e];
    if (e == 0) {
        for (int n = 0; n <= s; n++) row_ptr[n] = 0;
    } else {
        int p = edge[2 * (e - 1)];
        for (int n = p + 1; n <= s; n++) row_ptr[n] = e;
    }
    if (e == NE - 1) {
        for (int n = s + 1; n <= NN; n++) row_ptr[n] = NE;
    }
}

// K1: item = emb @ W_scale + b_scale (bf16), fused a_src/a_dst. One wave per
// 16 nodes. ALL loads (8 emb float4 + 32 WT short8) issued before any compute.
__global__ void __launch_bounds__(256) k_gemm(const float* __restrict__ emb,
        const unsigned short* __restrict__ WT, const float* __restrict__ b_scale,
        const float* __restrict__ W_att, unsigned short* __restrict__ item,
        float* __restrict__ a_src, float* __restrict__ a_dst,
        const float* __restrict__ b_att) {
    int wave = blockIdx.x * 4 + (threadIdx.x >> 6);
    int lane = threadIdx.x & 63;
    int base = wave * 16;
    if (base >= NN) return;
    int m = lane & 15, q = lane >> 4;
    int node = base + m;
    bool valid = node < NN;
    int row = valid ? node : NN - 1;

    // ---- phase 1: issue every independent load (MLP = 40 requests/wave) ----
    const float* bp = emb + (long)row * DD + q * 8;     // HBM stream: issue FIRST
    float4 f0[4], f1[4];
    #pragma unroll
    for (int ks = 0; ks < 4; ks++) {
        f0[ks] = *(const float4*)(bp + ks * 32);
        f1[ks] = *(const float4*)(bp + ks * 32 + 4);
    }
    short8 a[8][4];                                     // all A-frags (WT is L1/L2-hot)
    #pragma unroll
    for (int ft = 0; ft < 8; ft++) {
        const unsigned short* wrow = WT + (ft * 16 + m) * DD + q * 8;
        #pragma unroll
        for (int ks = 0; ks < 4; ks++)
            a[ft][ks] = *(const short8*)(wrow + ks * 32);
    }

    // ---- phase 2: convert emb row to bf16 B-frags ----
    short8 b[4];
    #pragma unroll
    for (int ks = 0; ks < 4; ks++) {
        b[ks][0] = (short)f2bf(f0[ks].x); b[ks][1] = (short)f2bf(f0[ks].y);
        b[ks][2] = (short)f2bf(f0[ks].z); b[ks][3] = (short)f2bf(f0[ks].w);
        b[ks][4] = (short)f2bf(f1[ks].x); b[ks][5] = (short)f2bf(f1[ks].y);
        b[ks][6] = (short)f2bf(f1[ks].z); b[ks][7] = (short)f2bf(f1[ks].w);
    }

    // ---- phase 3: MFMA + epilogue (identical math to rounds 1-6) ----
    float p_src = 0.f, p_dst = 0.f;

    #pragma unroll
    for (int ft = 0; ft < 8; ft++) {
        floatx4 acc = {0.f, 0.f, 0.f, 0.f};
        #pragma unroll
        for (int ks = 0; ks < 4; ks++)
            acc = __builtin_amdgcn_mfma_f32_16x16x32_bf16(a[ft][ks], b[ks], acc, 0, 0, 0);
        int fo = ft * 16 + q * 4;
        float4 bs = *(const float4*)(b_scale + fo);
        float4 ws = *(const float4*)(W_att + fo);
        float4 wd = *(const float4*)(W_att + DD + fo);
        float v0 = acc[0] + bs.x, v1 = acc[1] + bs.y;
        float v2 = acc[2] + bs.z, v3 = acc[3] + bs.w;
        if (valid) {
            uint2 pk;
            pk.x = (unsigned)f2bf(v0) | ((unsigned)f2bf(v1) << 16);
            pk.y = (unsigned)f2bf(v2) | ((unsigned)f2bf(v3) << 16);
            *(uint2*)(item + (long)node * DD + fo) = pk;
        }
        p_src += v0 * ws.x + v1 * ws.y + v2 * ws.z + v3 * ws.w;
        p_dst += v0 * wd.x + v1 * wd.y + v2 * wd.z + v3 * wd.w;
    }
    // reduce over q (lane bits 4,5); node is fixed within the reduction
    p_src += __shfl_xor(p_src, 16, 64); p_src += __shfl_xor(p_src, 32, 64);
    p_dst += __shfl_xor(p_dst, 16, 64); p_dst += __shfl_xor(p_dst, 32, 64);
    if (q == 0 && valid) { a_src[node] = p_src + b_att[0]; a_dst[node] = p_dst; }
}

// K2: one 16-lane group per node (byte-identical to round 1).
#define ACC8(S, U) \
    acc[0] += (S) * bflo((U).x); acc[1] += (S) * bfhi((U).x); \
    acc[2] += (S) * bflo((U).y); acc[3] += (S) * bfhi((U).y); \
    acc[4] += (S) * bflo((U).z); acc[5] += (S) * bfhi((U).z); \
    acc[6] += (S) * bflo((U).w); acc[7] += (S) * bfhi((U).w);

__global__ void __launch_bounds__(256) k_agg(const int* __restrict__ edge,
        const int* __restrict__ row_ptr, const unsigned short* __restrict__ item,
        const float* __restrict__ a_src, const float* __restrict__ a_dst,
        float* __restrict__ out) {
    int n = blockIdx.x * 16 + (threadIdx.x >> 4);
    int t = threadIdx.x & 15;
    if (n >= NN) return;

    int start = row_ptr[n];
    int len = row_ptr[n + 1] - start;
    float* op = out + (long)n * DD + t * 8;

    if (len <= 0) {
        float4 h = make_float4(0.5f, 0.5f, 0.5f, 0.5f);   // sigmoid(0)
        *(float4*)op = h;
        *(float4*)(op + 4) = h;
        return;
    }

    float asrc = a_src[n];                 // b_att already folded in
    const int* dp = edge + 2 * start + 1;  // dst stream, stride-2 ints
    const unsigned short* ip = item + t * 8;

    float acc[8] = {0.f, 0.f, 0.f, 0.f, 0.f, 0.f, 0.f, 0.f};
    float ssum = 0.f;

    for (int j = 0; j < len; j += 16) {
        int jj = j + t;
        int idx = jj < len ? jj : len - 1;
        int d = dp[2 * idx];               // 16 lanes, contiguous 128 B window
        float x = a_dst[d];                // scattered 4 B, L2-resident (200 KB)
        float s = (jj < len) ? score(asrc + x) : 0.f;
        ssum += s;

        int cnt = len - j;
        if (cnt > 16) cnt = 16;
        int kk = 0;
        for (; kk + 4 <= cnt; kk += 4) {
            int d0 = __shfl(d, kk, 16),     d1 = __shfl(d, kk + 1, 16);
            int d2 = __shfl(d, kk + 2, 16), d3 = __shfl(d, kk + 3, 16);
            float s0 = __shfl(s, kk, 16),     s1 = __shfl(s, kk + 1, 16);
            float s2 = __shfl(s, kk + 2, 16), s3 = __shfl(s, kk + 3, 16);
            uint4 u0 = *(const uint4*)(ip + (long)d0 * DD);
            uint4 u1 = *(const uint4*)(ip + (long)d1 * DD);
            uint4 u2 = *(const uint4*)(ip + (long)d2 * DD);
            uint4 u3 = *(const uint4*)(ip + (long)d3 * DD);
            ACC8(s0, u0);
            ACC8(s1, u1);
            ACC8(s2, u2);
            ACC8(s3, u3);
        }
        for (; kk < cnt; kk++) {
            int d0 = __shfl(d, kk, 16);
            float s0 = __shfl(s, kk, 16);
            uint4 u0 = *(const uint4*)(ip + (long)d0 * DD);
            ACC8(s0, u0);
        }
    }

    // ssum reduce across the 16-lane group only (acc needs no reduction)
    ssum += __shfl_xor(ssum, 1, 16);
    ssum += __shfl_xor(ssum, 2, 16);
    ssum += __shfl_xor(ssum, 4, 16);
    ssum += __shfl_xor(ssum, 8, 16);
    float inv = 1.f / ssum;

    float4 o0, o1;
    o0.x = 1.f / (1.f + __expf(-acc[0] * inv));
    o0.y = 1.f / (1.f + __expf(-acc[1] * inv));
    o0.z = 1.f / (1.f + __expf(-acc[2] * inv));
    o0.w = 1.f / (1.f + __expf(-acc[3] * inv));
    o1.x = 1.f / (1.f + __expf(-acc[4] * inv));
    o1.y = 1.f / (1.f + __expf(-acc[5] * inv));
    o1.z = 1.f / (1.f + __expf(-acc[6] * inv));
    o1.w = 1.f / (1.f + __expf(-acc[7] * inv));
    *(float4*)op = o0;
    *(float4*)(op + 4) = o1;
}

extern "C" void kernel_launch(void* const* d_in, const int* in_sizes, int n_in,
                              void* d_out, int out_size, void* d_ws, size_t ws_size,
                              hipStream_t stream) {
    const int*   edge    = (const int*)d_in[0];
    const float* emb     = (const float*)d_in[1];
    const float* W_scale = (const float*)d_in[2];
    const float* b_scale = (const float*)d_in[3];
    const float* W_att   = (const float*)d_in[4];
    const float* b_att   = (const float*)d_in[5];
    float* out = (float*)d_out;

    char* ws = (char*)d_ws;
    int*            row_ptr = (int*)(ws);                                // 200832 B
    float*          a_src   = (float*)(ws + 200832);                     // 200192 B
    float*          a_dst   = (float*)(ws + 401024);                     // 200192 B
    unsigned short* item    = (unsigned short*)(ws + 601216);            // 12800256 B
    unsigned short* WT      = (unsigned short*)(ws + 13401472);          // 32768 B

    int node_blocks = (NN + 15) / 16;        // one 16-lane group per node

    k_pre  <<<TR_BLOCKS + EDGE_BLOCKS, 256, 0, stream>>>(W_scale, edge, WT, row_ptr);
    k_gemm <<<GEMM_BLOCKS,             256, 0, stream>>>(emb, WT, b_scale, W_att,
                                                         item, a_src, a_dst, b_att);
    k_agg  <<<node_blocks,             256, 0, stream>>>(edge, row_ptr, item,
                                                         a_src, a_dst, out);
}